// Round 1
// baseline (1393.801 us; speedup 1.0000x reference)
//
#include <hip/hip_runtime.h>
#include <stdint.h>

#define T_TOK 2048
#define DMODEL 1024
#define FDIM 4096
#define NEXP 8
#define CAP 2048

#define BM 128
#define BN 128
#define BK 32
#define LDS_LD 40   // 32 + 8 pad, keeps 16B alignment for b128, breaks pow2 banking

typedef __attribute__((ext_vector_type(8))) short short8;       // 8 bf16 (4 VGPRs)
typedef __attribute__((ext_vector_type(4))) float f32x4;
typedef __attribute__((ext_vector_type(4))) unsigned short us4;
typedef __attribute__((ext_vector_type(8))) unsigned short us8;

__device__ __forceinline__ unsigned short f2bf(float f) {
  union { float f; unsigned int u; } v; v.f = f;
  unsigned int r = (v.u + 0x7fffu + ((v.u >> 16) & 1u)) >> 16;  // RNE
  return (unsigned short)r;
}

// ---------------- gating: logits, softmax, top-2, routing lists ----------------
__global__ void gate_kernel(const float* __restrict__ x, const float* __restrict__ Wg,
                            const float* __restrict__ bg,
                            int* cnt, int* top1cnt, float* sumprob,
                            int* list, float* wlist) {
  int wave = threadIdx.x >> 6;
  int lane = threadIdx.x & 63;
  int t = blockIdx.x * 4 + wave;
  if (t >= T_TOK) return;
  float acc[8];
#pragma unroll
  for (int e = 0; e < 8; e++) acc[e] = 0.f;
  const float* xr = x + (size_t)t * DMODEL;
  for (int d = lane; d < DMODEL; d += 64) {
    float xv = xr[d];
    const float* wr = Wg + d * 8;
#pragma unroll
    for (int e = 0; e < 8; e++) acc[e] += xv * wr[e];
  }
#pragma unroll
  for (int off = 32; off > 0; off >>= 1) {
#pragma unroll
    for (int e = 0; e < 8; e++) acc[e] += __shfl_down(acc[e], off);
  }
  if (lane == 0) {
    float p[8];
    float m = -1e30f;
#pragma unroll
    for (int e = 0; e < 8; e++) { p[e] = acc[e] + bg[e]; m = fmaxf(m, p[e]); }
    float s = 0.f;
#pragma unroll
    for (int e = 0; e < 8; e++) { p[e] = __expf(p[e] - m); s += p[e]; }
    float inv = 1.f / s;
#pragma unroll
    for (int e = 0; e < 8; e++) p[e] *= inv;
    int e1 = 0; float p1 = p[0];
#pragma unroll
    for (int e = 1; e < 8; e++) if (p[e] > p1) { p1 = p[e]; e1 = e; }   // strict > : lowest idx wins ties
    int e2 = -1; float p2 = -1.f;
#pragma unroll
    for (int e = 0; e < 8; e++) if (e != e1 && p[e] > p2) { p2 = p[e]; e2 = e; }
    atomicAdd(top1cnt + e1, 1);
#pragma unroll
    for (int e = 0; e < 8; e++) atomicAdd(sumprob + e, p[e]);
    int pos1 = atomicAdd(cnt + e1, 1);
    list[e1 * CAP + pos1] = t; wlist[e1 * CAP + pos1] = p1;
    int pos2 = atomicAdd(cnt + e2, 1);
    list[e2 * CAP + pos2] = t; wlist[e2 * CAP + pos2] = p2;
  }
}

// ---------------- offsets (prefix sum) + aux loss ----------------
__global__ void offs_aux_kernel(const int* cnt, const int* top1cnt, const float* sumprob,
                                int* offs, float* out_aux) {
  if (threadIdx.x == 0 && blockIdx.x == 0) {
    int off = 0;
    float aux = 0.f;
    for (int e = 0; e < 8; e++) {
      offs[e] = off; off += cnt[e];
      aux += ((float)top1cnt[e] / ((float)T_TOK + 1e-8f)) * (sumprob[e] / (float)T_TOK);
    }
    *out_aux = aux * (float)NEXP;
  }
}

// ---------------- gather x rows into compact bf16 buffer ----------------
__global__ void gather_kernel(const float* __restrict__ x, const int* __restrict__ list,
                              const int* __restrict__ cnt, const int* __restrict__ offs,
                              unsigned short* __restrict__ xg) {
  int e = blockIdx.x >> 11;
  int i = blockIdx.x & 2047;
  if (i >= cnt[e]) return;
  int t = list[e * CAP + i];
  int row = offs[e] + i;
  const f32x4* src = (const f32x4*)(x + (size_t)t * DMODEL);
  us4* dst = (us4*)(xg + (size_t)row * DMODEL);
  int j = threadIdx.x;                 // 256 threads x 4 elems = 1024
  f32x4 v = src[j];
  us4 o; o.x = f2bf(v.x); o.y = f2bf(v.y); o.z = f2bf(v.z); o.w = f2bf(v.w);
  dst[j] = o;
}

// ---------------- GEMM1: h = relu(xg @ W1[e] + b1[e]) ----------------
__launch_bounds__(256, 2)
__global__ void gemm1_kernel(const unsigned short* __restrict__ xg,
                             const float* __restrict__ W1, const float* __restrict__ b1,
                             const int* __restrict__ cnt, const int* __restrict__ offs,
                             unsigned short* __restrict__ h) {
  int e = blockIdx.x >> 4;
  int mt = blockIdx.x & 15;
  int count = cnt[e];
  if (mt * BM >= count) return;
  int n0 = blockIdx.y * BN;
  int base = offs[e];
  const unsigned short* A = xg + (size_t)(base + mt * BM) * DMODEL;
  const float* B = W1 + (size_t)e * DMODEL * FDIM + n0;

  __shared__ unsigned short As[BM * LDS_LD];
  __shared__ unsigned short Bs[BN * LDS_LD];   // [n][k]

  int tid = threadIdx.x;
  int wave = tid >> 6, lane = tid & 63;
  int wr = wave >> 1, wc = wave & 1;
  int l16 = lane & 15, quad = lane >> 4;

  f32x4 acc[4][4];
#pragma unroll
  for (int i = 0; i < 4; i++)
#pragma unroll
    for (int j = 0; j < 4; j++)
#pragma unroll
      for (int r = 0; r < 4; r++) acc[i][j][r] = 0.f;

  for (int kb = 0; kb < DMODEL / BK; kb++) {
    // A stage: 128 rows x 32 bf16, vector 16B copies
    for (int s = tid; s < 512; s += 256) {
      int row = s >> 2, seg = s & 3;
      us8 v = *(const us8*)(A + (size_t)row * DMODEL + kb * BK + seg * 8);
      *(us8*)&As[row * LDS_LD + seg * 8] = v;
    }
    // B stage: fp32 [k][n] -> bf16 LDS [n][k] (transpose so frag reads are b128)
    {
      int n = tid & 127;
      for (int kq = (tid >> 7); kq < 8; kq += 2) {
        int k4 = kq * 4;
        const float* bp = B + (size_t)(kb * BK + k4) * FDIM + n;
        float f0 = bp[0];
        float f1 = bp[FDIM];
        float f2 = bp[2 * (size_t)FDIM];
        float f3 = bp[3 * (size_t)FDIM];
        us4 pk; pk.x = f2bf(f0); pk.y = f2bf(f1); pk.z = f2bf(f2); pk.w = f2bf(f3);
        *(us4*)&Bs[n * LDS_LD + k4] = pk;
      }
    }
    __syncthreads();
    short8 af[4], bf[4];
#pragma unroll
    for (int i = 0; i < 4; i++)
      af[i] = *(const short8*)&As[(wr * 64 + i * 16 + l16) * LDS_LD + quad * 8];
#pragma unroll
    for (int j = 0; j < 4; j++)
      bf[j] = *(const short8*)&Bs[(wc * 64 + j * 16 + l16) * LDS_LD + quad * 8];
#pragma unroll
    for (int i = 0; i < 4; i++)
#pragma unroll
      for (int j = 0; j < 4; j++)
        acc[i][j] = __builtin_amdgcn_mfma_f32_16x16x32_bf16(af[i], bf[j], acc[i][j], 0, 0, 0);
    __syncthreads();
  }

#pragma unroll
  for (int j = 0; j < 4; j++) {
    int ncol = n0 + wc * 64 + j * 16 + l16;
    float bias = b1[e * FDIM + ncol];
#pragma unroll
    for (int i = 0; i < 4; i++) {
      int rbase = mt * BM + wr * 64 + i * 16 + quad * 4;
#pragma unroll
      for (int r = 0; r < 4; r++) {
        int row = rbase + r;
        if (row < count) {
          float v = fmaxf(acc[i][j][r] + bias, 0.f);
          h[(size_t)(base + row) * FDIM + ncol] = f2bf(v);
        }
      }
    }
  }
}

// ---------------- GEMM2: out[tok] += w * (h @ W2[e] + b2[e]) ----------------
__launch_bounds__(256, 2)
__global__ void gemm2_kernel(const unsigned short* __restrict__ h,
                             const float* __restrict__ W2, const float* __restrict__ b2,
                             const int* __restrict__ cnt, const int* __restrict__ offs,
                             const int* __restrict__ list, const float* __restrict__ wlist,
                             float* __restrict__ out) {
  int e = blockIdx.x >> 4;
  int mt = blockIdx.x & 15;
  int count = cnt[e];
  if (mt * BM >= count) return;
  int n0 = blockIdx.y * BN;
  int base = offs[e];
  const unsigned short* A = h + (size_t)(base + mt * BM) * FDIM;
  const float* B = W2 + (size_t)e * FDIM * DMODEL + n0;

  __shared__ unsigned short As[BM * LDS_LD];
  __shared__ unsigned short Bs[BN * LDS_LD];

  int tid = threadIdx.x;
  int wave = tid >> 6, lane = tid & 63;
  int wr = wave >> 1, wc = wave & 1;
  int l16 = lane & 15, quad = lane >> 4;

  f32x4 acc[4][4];
#pragma unroll
  for (int i = 0; i < 4; i++)
#pragma unroll
    for (int j = 0; j < 4; j++)
#pragma unroll
      for (int r = 0; r < 4; r++) acc[i][j][r] = 0.f;

  for (int kb = 0; kb < FDIM / BK; kb++) {
    for (int s = tid; s < 512; s += 256) {
      int row = s >> 2, seg = s & 3;
      us8 v = *(const us8*)(A + (size_t)row * FDIM + kb * BK + seg * 8);
      *(us8*)&As[row * LDS_LD + seg * 8] = v;
    }
    {
      int n = tid & 127;
      for (int kq = (tid >> 7); kq < 8; kq += 2) {
        int k4 = kq * 4;
        const float* bp = B + (size_t)(kb * BK + k4) * DMODEL + n;
        float f0 = bp[0];
        float f1 = bp[DMODEL];
        float f2 = bp[2 * (size_t)DMODEL];
        float f3 = bp[3 * (size_t)DMODEL];
        us4 pk; pk.x = f2bf(f0); pk.y = f2bf(f1); pk.z = f2bf(f2); pk.w = f2bf(f3);
        *(us4*)&Bs[n * LDS_LD + k4] = pk;
      }
    }
    __syncthreads();
    short8 af[4], bf[4];
#pragma unroll
    for (int i = 0; i < 4; i++)
      af[i] = *(const short8*)&As[(wr * 64 + i * 16 + l16) * LDS_LD + quad * 8];
#pragma unroll
    for (int j = 0; j < 4; j++)
      bf[j] = *(const short8*)&Bs[(wc * 64 + j * 16 + l16) * LDS_LD + quad * 8];
#pragma unroll
    for (int i = 0; i < 4; i++)
#pragma unroll
      for (int j = 0; j < 4; j++)
        acc[i][j] = __builtin_amdgcn_mfma_f32_16x16x32_bf16(af[i], bf[j], acc[i][j], 0, 0, 0);
    __syncthreads();
  }

  float b2v[4];
#pragma unroll
  for (int j = 0; j < 4; j++) b2v[j] = b2[e * DMODEL + n0 + wc * 64 + j * 16 + l16];

#pragma unroll
  for (int i = 0; i < 4; i++) {
    int rbase = mt * BM + wr * 64 + i * 16 + quad * 4;
#pragma unroll
    for (int r = 0; r < 4; r++) {
      int row = rbase + r;
      if (row >= count) continue;
      int tok = list[e * CAP + row];
      float w = wlist[e * CAP + row];
#pragma unroll
      for (int j = 0; j < 4; j++) {
        int ncol = n0 + wc * 64 + j * 16 + l16;
        float v = w * (acc[i][j][r] + b2v[j]);
        atomicAdd(out + (size_t)tok * DMODEL + ncol, v);
      }
    }
  }
}

extern "C" void kernel_launch(void* const* d_in, const int* in_sizes, int n_in,
                              void* d_out, int out_size, void* d_ws, size_t ws_size,
                              hipStream_t stream) {
  const float* x  = (const float*)d_in[0];
  const float* Wg = (const float*)d_in[1];
  const float* bg = (const float*)d_in[2];
  const float* W1 = (const float*)d_in[3];
  const float* b1 = (const float*)d_in[4];
  const float* W2 = (const float*)d_in[5];
  const float* b2 = (const float*)d_in[6];
  float* out = (float*)d_out;

  char* ws = (char*)d_ws;
  int*   cnt     = (int*)(ws + 0);
  int*   top1cnt = (int*)(ws + 32);
  int*   offs    = (int*)(ws + 64);
  float* sumprob = (float*)(ws + 96);
  int*   list    = (int*)(ws + 1024);
  float* wlist   = (float*)(ws + 1024 + 65536);
  unsigned short* xg = (unsigned short*)(ws + (256u << 10));   // (4096+128) x 1024 bf16 = 8.65 MB
  unsigned short* h  = (unsigned short*)(ws + (16u << 20));    // (4096+128) x 4096 bf16 = 34.6 MB

  hipMemsetAsync(ws, 0, 1024, stream);
  hipMemsetAsync(d_out, 0, (size_t)out_size * sizeof(float), stream);

  gate_kernel<<<T_TOK / 4, 256, 0, stream>>>(x, Wg, bg, cnt, top1cnt, sumprob, list, wlist);
  offs_aux_kernel<<<1, 64, 0, stream>>>(cnt, top1cnt, sumprob, offs, out + (size_t)T_TOK * DMODEL);
  gather_kernel<<<NEXP * CAP, 256, 0, stream>>>(x, list, cnt, offs, xg);
  gemm1_kernel<<<dim3(NEXP * 16, FDIM / BN), 256, 0, stream>>>(xg, W1, b1, cnt, offs, h);
  gemm2_kernel<<<dim3(NEXP * 16, DMODEL / BN), 256, 0, stream>>>(h, W2, b2, cnt, offs, list, wlist, out);
}

// Round 4
// 946.574 us; speedup vs baseline: 1.4725x; 1.4725x over previous
//
#include <hip/hip_runtime.h>
#include <stdint.h>

#define T_TOK 2048
#define DMODEL 1024
#define FDIM 4096
#define NEXP 8
#define CAP 2048

typedef __attribute__((ext_vector_type(8))) short short8;       // 8 bf16 (4 VGPRs)
typedef __attribute__((ext_vector_type(4))) float f32x4;
typedef __attribute__((ext_vector_type(4))) unsigned short us4;
typedef __attribute__((ext_vector_type(8))) unsigned short us8;

__device__ __forceinline__ unsigned short f2bf(float f) {
  union { float f; unsigned int u; } v; v.f = f;
  unsigned int r = (v.u + 0x7fffu + ((v.u >> 16) & 1u)) >> 16;  // RNE
  return (unsigned short)r;
}

// async global->LDS 16B per lane; LDS dest = wave-uniform base + lane*16
__device__ __forceinline__ void async16(const unsigned short* g, unsigned short* l) {
  __builtin_amdgcn_global_load_lds(
      (const __attribute__((address_space(1))) unsigned int*)g,
      (__attribute__((address_space(3))) unsigned int*)l,
      16, 0, 0);
}

// ---------------- gating: logits, softmax, top-2, routing lists ----------------
__global__ void gate_kernel(const float* __restrict__ x, const float* __restrict__ Wg,
                            const float* __restrict__ bg,
                            int* cnt, int* top1cnt, float* sumprob,
                            int* list, float* wlist) {
  int wave = threadIdx.x >> 6;
  int lane = threadIdx.x & 63;
  int t = blockIdx.x * 4 + wave;
  if (t >= T_TOK) return;
  float acc[8];
#pragma unroll
  for (int e = 0; e < 8; e++) acc[e] = 0.f;
  const float* xr = x + (size_t)t * DMODEL;
  for (int d = lane; d < DMODEL; d += 64) {
    float xv = xr[d];
    const float* wr = Wg + d * 8;
#pragma unroll
    for (int e = 0; e < 8; e++) acc[e] += xv * wr[e];
  }
#pragma unroll
  for (int off = 32; off > 0; off >>= 1) {
#pragma unroll
    for (int e = 0; e < 8; e++) acc[e] += __shfl_down(acc[e], off);
  }
  if (lane == 0) {
    float p[8];
    float m = -1e30f;
#pragma unroll
    for (int e = 0; e < 8; e++) { p[e] = acc[e] + bg[e]; m = fmaxf(m, p[e]); }
    float s = 0.f;
#pragma unroll
    for (int e = 0; e < 8; e++) { p[e] = __expf(p[e] - m); s += p[e]; }
    float inv = 1.f / s;
#pragma unroll
    for (int e = 0; e < 8; e++) p[e] *= inv;
    int e1 = 0; float p1 = p[0];
#pragma unroll
    for (int e = 1; e < 8; e++) if (p[e] > p1) { p1 = p[e]; e1 = e; }   // strict > : lowest idx wins ties
    int e2 = -1; float p2 = -1.f;
#pragma unroll
    for (int e = 0; e < 8; e++) if (e != e1 && p[e] > p2) { p2 = p[e]; e2 = e; }
    atomicAdd(top1cnt + e1, 1);
#pragma unroll
    for (int e = 0; e < 8; e++) atomicAdd(sumprob + e, p[e]);
    int pos1 = atomicAdd(cnt + e1, 1);
    list[e1 * CAP + pos1] = t; wlist[e1 * CAP + pos1] = p1;
    int pos2 = atomicAdd(cnt + e2, 1);
    list[e2 * CAP + pos2] = t; wlist[e2 * CAP + pos2] = p2;
  }
}

// ---------------- offsets (prefix sum) + aux loss ----------------
__global__ void offs_aux_kernel(const int* cnt, const int* top1cnt, const float* sumprob,
                                int* offs, float* out_aux) {
  if (threadIdx.x == 0 && blockIdx.x == 0) {
    int off = 0;
    float aux = 0.f;
    for (int e = 0; e < 8; e++) {
      offs[e] = off; off += cnt[e];
      aux += ((float)top1cnt[e] / ((float)T_TOK + 1e-8f)) * (sumprob[e] / (float)T_TOK);
    }
    *out_aux = aux * (float)NEXP;
  }
}

// ---------------- gather x rows into compact bf16 buffer ----------------
__global__ void gather_kernel(const float* __restrict__ x, const int* __restrict__ list,
                              const int* __restrict__ cnt, const int* __restrict__ offs,
                              unsigned short* __restrict__ xg) {
  int e = blockIdx.x >> 11;
  int i = blockIdx.x & 2047;
  if (i >= cnt[e]) return;
  int t = list[e * CAP + i];
  int row = offs[e] + i;
  const f32x4* src = (const f32x4*)(x + (size_t)t * DMODEL);
  us4* dst = (us4*)(xg + (size_t)row * DMODEL);
  int j = threadIdx.x;                 // 256 threads x 4 elems = 1024
  f32x4 v = src[j];
  us4 o; o.x = f2bf(v.x); o.y = f2bf(v.y); o.z = f2bf(v.z); o.w = f2bf(v.w);
  dst[j] = o;
}

// ---- convert+transpose slice: fp32 [E][K][Nfull] cols [n_off,n_off+NS) -> bf16 [E][NS][K] ----
__launch_bounds__(256)
__global__ void convt_kernel(const float* __restrict__ in, unsigned short* __restrict__ out,
                             int K, int Nfull, int NS, int n_off) {
  int e = blockIdx.y;
  int ntn = NS >> 6;
  int tk = blockIdx.x / ntn, tn = blockIdx.x % ntn;
  const float* src = in + (size_t)e * K * Nfull + (size_t)(tk * 64) * Nfull + n_off + tn * 64;
  unsigned short* dst = out + (size_t)e * NS * K + (size_t)(tn * 64) * K + tk * 64;
  __shared__ unsigned short Ls[64 * 72];
  int t = threadIdx.x;
  int k = t >> 4, n4 = (t & 15) * 4;
#pragma unroll
  for (int i = 0; i < 4; i++) {
    int kk = k + 16 * i;
    f32x4 v = *(const f32x4*)&src[(size_t)kk * Nfull + n4];
    Ls[(n4 + 0) * 72 + kk] = f2bf(v.x);
    Ls[(n4 + 1) * 72 + kk] = f2bf(v.y);
    Ls[(n4 + 2) * 72 + kk] = f2bf(v.z);
    Ls[(n4 + 3) * 72 + kk] = f2bf(v.w);
  }
  __syncthreads();
  int n = t >> 3, k8 = (t & 7) * 8;
#pragma unroll
  for (int j = 0; j < 2; j++) {
    int nn = n + 32 * j;
    us8 v = *(const us8*)&Ls[nn * 72 + k8];
    *(us8*)&dst[(size_t)nn * K + k8] = v;
  }
}

// ---------------- GEMM1 slice: h[:, n_off:n_off+NS] = relu(xg @ W1slice + b1) ----------------
__launch_bounds__(256)
__global__ void gemm1_kernel(const unsigned short* __restrict__ xg,
                             const unsigned short* __restrict__ Wt,   // [E][NS][D] bf16
                             const float* __restrict__ b1,
                             const int* __restrict__ cnt, const int* __restrict__ offs,
                             unsigned short* __restrict__ h, int NS, int n_off) {
  int e = blockIdx.x >> 4;
  int mt = blockIdx.x & 15;
  int count = cnt[e];
  if (mt * 128 >= count) return;
  int nloc = blockIdx.y * 128;
  int base = offs[e];
  const unsigned short* A = xg + (size_t)(base + mt * 128) * DMODEL;
  const unsigned short* B = Wt + (size_t)e * NS * DMODEL + (size_t)nloc * DMODEL;

  __shared__ unsigned short As[128 * 32];
  __shared__ unsigned short Bs[128 * 32];

  int tid = threadIdx.x;
  int w = tid >> 6, lane = tid & 63;
  int wr = w >> 1, wc = w & 1;
  int l16 = lane & 15, quad = lane >> 4;
  int lrow = lane >> 2, lseg = lane & 3;

  f32x4 acc[4][4];
#pragma unroll
  for (int i = 0; i < 4; i++)
#pragma unroll
    for (int j = 0; j < 4; j++)
#pragma unroll
      for (int r = 0; r < 4; r++) acc[i][j][r] = 0.f;

  const unsigned short* Ab = A + (size_t)(w * 32 + lrow) * DMODEL + lseg * 8;
  const unsigned short* Bb = B + (size_t)(w * 32 + lrow) * DMODEL + lseg * 8;
  unsigned short* Ad0 = &As[(w * 32) * 32];
  unsigned short* Ad1 = &As[(w * 32 + 16) * 32];
  unsigned short* Bd0 = &Bs[(w * 32) * 32];
  unsigned short* Bd1 = &Bs[(w * 32 + 16) * 32];

  for (int kb = 0; kb < DMODEL / 32; kb++) {
    int ko = kb * 32;
    async16(Ab + ko, Ad0);
    async16(Ab + ko + 16 * DMODEL, Ad1);
    async16(Bb + ko, Bd0);
    async16(Bb + ko + 16 * DMODEL, Bd1);
    __syncthreads();
    short8 af[4], bf[4];
#pragma unroll
    for (int i = 0; i < 4; i++)
      af[i] = *(const short8*)&As[(wr * 64 + i * 16 + l16) * 32 + quad * 8];
#pragma unroll
    for (int j = 0; j < 4; j++)
      bf[j] = *(const short8*)&Bs[(wc * 64 + j * 16 + l16) * 32 + quad * 8];
#pragma unroll
    for (int i = 0; i < 4; i++)
#pragma unroll
      for (int j = 0; j < 4; j++)
        acc[i][j] = __builtin_amdgcn_mfma_f32_16x16x32_bf16(af[i], bf[j], acc[i][j], 0, 0, 0);
    __syncthreads();
  }

  // guard row<count: packed expert rows — unguarded writes clobber next expert (round-2 bug)
#pragma unroll
  for (int j = 0; j < 4; j++) {
    int ncol = n_off + nloc + wc * 64 + j * 16 + l16;
    float bias = b1[e * FDIM + ncol];
#pragma unroll
    for (int i = 0; i < 4; i++) {
      int rbase = mt * 128 + wr * 64 + i * 16 + quad * 4;
#pragma unroll
      for (int r = 0; r < 4; r++) {
        int row = rbase + r;
        if (row < count) {
          float v = fmaxf(acc[i][j][r] + bias, 0.f);
          h[(size_t)(base + row) * FDIM + ncol] = f2bf(v);
        }
      }
    }
  }
}

// ---------------- GEMM2 slice: out[tok, n] += w * (h @ W2slice + b2) ----------------
__launch_bounds__(256)
__global__ void gemm2_kernel(const unsigned short* __restrict__ h,
                             const unsigned short* __restrict__ Wt,   // [E][NS][F] bf16
                             const float* __restrict__ b2,
                             const int* __restrict__ cnt, const int* __restrict__ offs,
                             const int* __restrict__ list, const float* __restrict__ wlist,
                             float* __restrict__ out, int NS, int n_off) {
  int e = blockIdx.x >> 4;
  int mt = blockIdx.x & 15;
  int count = cnt[e];
  if (mt * 128 >= count) return;
  int nloc = blockIdx.y * 128;
  int base = offs[e];
  const unsigned short* A = h + (size_t)(base + mt * 128) * FDIM;
  const unsigned short* B = Wt + (size_t)e * NS * FDIM + (size_t)nloc * FDIM;

  __shared__ unsigned short As[128 * 32];
  __shared__ unsigned short Bs[128 * 32];

  int tid = threadIdx.x;
  int w = tid >> 6, lane = tid & 63;
  int wr = w >> 1, wc = w & 1;
  int l16 = lane & 15, quad = lane >> 4;
  int lrow = lane >> 2, lseg = lane & 3;

  f32x4 acc[4][4];
#pragma unroll
  for (int i = 0; i < 4; i++)
#pragma unroll
    for (int j = 0; j < 4; j++)
#pragma unroll
      for (int r = 0; r < 4; r++) acc[i][j][r] = 0.f;

  const unsigned short* Ab = A + (size_t)(w * 32 + lrow) * FDIM + lseg * 8;
  const unsigned short* Bb = B + (size_t)(w * 32 + lrow) * FDIM + lseg * 8;
  unsigned short* Ad0 = &As[(w * 32) * 32];
  unsigned short* Ad1 = &As[(w * 32 + 16) * 32];
  unsigned short* Bd0 = &Bs[(w * 32) * 32];
  unsigned short* Bd1 = &Bs[(w * 32 + 16) * 32];

  for (int kb = 0; kb < FDIM / 32; kb++) {
    int ko = kb * 32;
    async16(Ab + ko, Ad0);
    async16(Ab + ko + 16 * FDIM, Ad1);
    async16(Bb + ko, Bd0);
    async16(Bb + ko + 16 * FDIM, Bd1);
    __syncthreads();
    short8 af[4], bf[4];
#pragma unroll
    for (int i = 0; i < 4; i++)
      af[i] = *(const short8*)&As[(wr * 64 + i * 16 + l16) * 32 + quad * 8];
#pragma unroll
    for (int j = 0; j < 4; j++)
      bf[j] = *(const short8*)&Bs[(wc * 64 + j * 16 + l16) * 32 + quad * 8];
#pragma unroll
    for (int i = 0; i < 4; i++)
#pragma unroll
      for (int j = 0; j < 4; j++)
        acc[i][j] = __builtin_amdgcn_mfma_f32_16x16x32_bf16(af[i], bf[j], acc[i][j], 0, 0, 0);
    __syncthreads();
  }

  float bv[4];
#pragma unroll
  for (int j = 0; j < 4; j++) bv[j] = b2[e * DMODEL + n_off + nloc + wc * 64 + j * 16 + l16];

#pragma unroll
  for (int i = 0; i < 4; i++) {
    int rbase = mt * 128 + wr * 64 + i * 16 + quad * 4;
#pragma unroll
    for (int r = 0; r < 4; r++) {
      int row = rbase + r;
      if (row >= count) continue;
      int tok = list[e * CAP + row];
      float wgt = wlist[e * CAP + row];
#pragma unroll
      for (int j = 0; j < 4; j++) {
        int ncol = n_off + nloc + wc * 64 + j * 16 + l16;
        atomicAdd(out + (size_t)tok * DMODEL + ncol, wgt * (acc[i][j][r] + bv[j]));
      }
    }
  }
}

extern "C" void kernel_launch(void* const* d_in, const int* in_sizes, int n_in,
                              void* d_out, int out_size, void* d_ws, size_t ws_size,
                              hipStream_t stream) {
  const float* x  = (const float*)d_in[0];
  const float* Wg = (const float*)d_in[1];
  const float* bg = (const float*)d_in[2];
  const float* W1 = (const float*)d_in[3];
  const float* b1 = (const float*)d_in[4];
  const float* W2 = (const float*)d_in[5];
  const float* b2 = (const float*)d_in[6];
  float* out = (float*)d_out;

  // Tight layout — ws usage proven safe up to 51.38 MB (round 1 passed full
  // timing at 51.38 MB). Buffer read-overruns from GEMM tile padding spill
  // into the NEXT buffer; those values feed only guarded-out accumulators.
  char* ws = (char*)d_ws;
  int*   cnt     = (int*)(ws + 0);
  int*   top1cnt = (int*)(ws + 32);
  int*   offs    = (int*)(ws + 64);
  float* sumprob = (float*)(ws + 96);
  int*   list    = (int*)(ws + 4096);                         // 64 KB
  float* wlist   = (float*)(ws + 4096 + 65536);               // 64 KB -> ends 135,168
  unsigned short* xg = (unsigned short*)(ws + 135168);        // 4096x1024 bf16 = 8,388,608 -> ends 8,523,776
  unsigned short* h  = (unsigned short*)(ws + 8523776);       // 4096x4096 bf16 = 33,554,432 -> ends 42,078,208
  unsigned short* Wt = (unsigned short*)(ws + 42078208);      // weight slice, 67,108,864/S bytes

  // pick slice count S from ws_size (stable across calls -> same work every call)
  const size_t baseBytes = 42078208ull;
  int S;
  if      (ws_size >= baseBytes + 67108864ull) S = 1;
  else if (ws_size >= baseBytes + 33554432ull) S = 2;
  else if (ws_size >= baseBytes + 16777216ull) S = 4;
  else                                         S = 8;   // needs 50.47 MB <= proven 51.38 MB

  hipMemsetAsync(ws, 0, 1024, stream);
  hipMemsetAsync(d_out, 0, (size_t)out_size * sizeof(float), stream);

  gate_kernel<<<T_TOK / 4, 256, 0, stream>>>(x, Wg, bg, cnt, top1cnt, sumprob, list, wlist);
  offs_aux_kernel<<<1, 64, 0, stream>>>(cnt, top1cnt, sumprob, offs, out + (size_t)T_TOK * DMODEL);
  gather_kernel<<<NEXP * CAP, 256, 0, stream>>>(x, list, cnt, offs, xg);

  int NS1 = FDIM / S;
  for (int s = 0; s < S; s++) {
    convt_kernel<<<dim3((DMODEL / 64) * (NS1 / 64), NEXP), 256, 0, stream>>>(
        W1, Wt, DMODEL, FDIM, NS1, s * NS1);
    gemm1_kernel<<<dim3(NEXP * 16, NS1 / 128), 256, 0, stream>>>(
        xg, Wt, b1, cnt, offs, h, NS1, s * NS1);
  }
  int NS2 = DMODEL / S;
  for (int s = 0; s < S; s++) {
    convt_kernel<<<dim3((FDIM / 64) * (NS2 / 64), NEXP), 256, 0, stream>>>(
        W2, Wt, FDIM, DMODEL, NS2, s * NS2);
    gemm2_kernel<<<dim3(NEXP * 16, NS2 / 128), 256, 0, stream>>>(
        h, Wt, b2, cnt, offs, list, wlist, out, NS2, s * NS2);
  }
}